// Round 1
// baseline (133.277 us; speedup 1.0000x reference)
//
#include <hip/hip_runtime.h>
#include <hip/hip_bf16.h>
#include <stdint.h>

#define SQ_  4096
#define SK_  4096
#define D_   1024
#define DV_  1024

typedef __attribute__((ext_vector_type(8))) __bf16 bf16x8;
typedef __attribute__((ext_vector_type(4))) float  f32x4;

__device__ __forceinline__ unsigned short f2bf(float f) {
  union { float f; unsigned u; } a; a.f = f;
  unsigned u = a.u;
  return (unsigned short)((u + 0x7FFFu + ((u >> 16) & 1u)) >> 16);  // RNE
}
__device__ __forceinline__ float bf2f(unsigned short h) {
  union { unsigned u; float f; } a; a.u = ((unsigned)h) << 16;
  return a.f;
}

__device__ __forceinline__ void gload_lds16(const void* gp, void* lp) {
  auto g1 = reinterpret_cast<__attribute__((address_space(1))) uint32_t*>(
      reinterpret_cast<uintptr_t>(gp));
  auto l3 = reinterpret_cast<__attribute__((address_space(3))) uint32_t*>(
      reinterpret_cast<uintptr_t>(lp));
  __builtin_amdgcn_global_load_lds(g1, l3, 16, 0, 0);
}

// ---------------- fp32 -> bf16 conversion (vectorized, 4/thread) -------------
__global__ void conv_kernel(const float* __restrict__ in,
                            unsigned short* __restrict__ out, int n4) {
  int i = blockIdx.x * blockDim.x + threadIdx.x;
  if (i >= n4) return;
  float4 v = reinterpret_cast<const float4*>(in)[i];
  ushort4 o;
  o.x = f2bf(v.x); o.y = f2bf(v.y); o.z = f2bf(v.z); o.w = f2bf(v.w);
  reinterpret_cast<ushort4*>(out)[i] = o;
}

// ---------------- column sums of E (softmax denominator) ---------------------
__global__ void colsum_kernel(const unsigned short* __restrict__ E,
                              float* __restrict__ l) {
  int j  = blockIdx.x * 256 + threadIdx.x;
  int i0 = blockIdx.y * 256;
  const unsigned short* p = E + (size_t)i0 * SK_ + j;
  float s = 0.f;
  #pragma unroll 8
  for (int i = 0; i < 256; ++i) { s += bf2f(*p); p += SK_; }
  atomicAdd(&l[j], s);
}

// ------------- V' = V / l, transposed to [DV][SK] bf16 -----------------------
__global__ void transv_kernel(const float* __restrict__ V,
                              const float* __restrict__ l,
                              unsigned short* __restrict__ Vt) {
  __shared__ float tile[64][65];
  int j0 = blockIdx.x * 64;           // SK dim
  int d0 = blockIdx.y * 64;           // DV dim
  int t  = threadIdx.x;
  int tr = t >> 6;                    // 0..3
  int tc = t & 63;                    // 0..63
  #pragma unroll
  for (int rr = 0; rr < 16; ++rr) {
    int j = rr * 4 + tr;
    tile[j][tc] = V[(size_t)(j0 + j) * DV_ + d0 + tc];
  }
  __syncthreads();
  float inv = 1.0f / l[j0 + tc];      // divisor indexed by j = tc
  #pragma unroll
  for (int rr = 0; rr < 16; ++rr) {
    int d = rr * 4 + tr;
    Vt[(size_t)(d0 + d) * SK_ + j0 + tc] = f2bf(tile[tc][d] * inv);
  }
}

// ---------------- GEMM: C[M][N] = A[M][K] * B[N][K]^T ------------------------
// A, B row-major with K contiguous (NT-gemm). bf16 inputs, fp32 accum.
// EXP epilogue: store bf16 exp(acc*scale); else store fp32 acc.
// LDS is XOR-swizzled: physical 16B slot (row,p) holds logical (row, p^(row&7));
// staging pre-swizzles the GLOBAL source (gload_lds writes linearly), reads
// apply the same XOR -> conflict-minimal ds_read_b128 (2-way).
template <int FM, int FN, bool EXP>
__global__ __launch_bounds__(256, 2)
void gemm_bt_kernel(const unsigned short* __restrict__ A,
                    const unsigned short* __restrict__ B,
                    void* __restrict__ C,
                    int N, int K, float scale) {
  constexpr int BM = FM * 32;
  constexpr int BN = FN * 32;
  constexpr int BK = 64;
  __shared__ __align__(16) unsigned short As[BM * BK];
  __shared__ __align__(16) unsigned short Bs[BN * BK];

  const int t    = threadIdx.x;
  const int lane = t & 63;
  const int wave = t >> 6;
  const int wr   = wave >> 1, wc = wave & 1;   // 2x2 wave grid
  const int lr   = lane & 15;                  // frag row(A)/col(B), D col
  const int lk   = lane >> 4;                  // k-group 0..3

  const int m0 = blockIdx.y * BM;
  const int n0 = blockIdx.x * BN;

  f32x4 acc[FM][FN] = {};

  for (int k0 = 0; k0 < K; k0 += BK) {
    // ---- stage A tile: BM rows x 64 k, 16B per slot, linear LDS dest ----
    #pragma unroll
    for (int it = 0; it < BM / 32; ++it) {
      int s = it * 256 + t;
      int row = s >> 3, p = s & 7;
      int k16 = p ^ (row & 7);                 // inverse-swizzled source
      gload_lds16(A + (size_t)(m0 + row) * K + k0 + k16 * 8, As + s * 8);
    }
    // ---- stage B tile ----
    #pragma unroll
    for (int it = 0; it < BN / 32; ++it) {
      int s = it * 256 + t;
      int row = s >> 3, p = s & 7;
      int k16 = p ^ (row & 7);
      gload_lds16(B + (size_t)(n0 + row) * K + k0 + k16 * 8, Bs + s * 8);
    }
    __syncthreads();

    #pragma unroll
    for (int kk = 0; kk < 2; ++kk) {
      bf16x8 af[FM], bfr[FN];
      #pragma unroll
      for (int m = 0; m < FM; ++m) {
        int r = wr * (FM * 16) + m * 16 + lr;
        int k16 = kk * 4 + lk;
        af[m] = *reinterpret_cast<const bf16x8*>(
            As + r * BK + ((k16 ^ (r & 7)) * 8));
      }
      #pragma unroll
      for (int n = 0; n < FN; ++n) {
        int r = wc * (FN * 16) + n * 16 + lr;
        int k16 = kk * 4 + lk;
        bfr[n] = *reinterpret_cast<const bf16x8*>(
            Bs + r * BK + ((k16 ^ (r & 7)) * 8));
      }
      #pragma unroll
      for (int m = 0; m < FM; ++m)
        #pragma unroll
        for (int n = 0; n < FN; ++n)
          acc[m][n] = __builtin_amdgcn_mfma_f32_16x16x32_bf16(
              af[m], bfr[n], acc[m][n], 0, 0, 0);
    }
    __syncthreads();
  }

  // ---- epilogue: D[row=(lane>>4)*4+r][col=lane&15] (m89/m91-verified) ----
  const int orow0 = m0 + wr * FM * 16 + lk * 4;
  const int ocol0 = n0 + wc * FN * 16 + lr;
  if (EXP) {
    unsigned short* O = (unsigned short*)C;
    #pragma unroll
    for (int m = 0; m < FM; ++m)
      #pragma unroll
      for (int n = 0; n < FN; ++n)
        #pragma unroll
        for (int r = 0; r < 4; ++r)
          O[(size_t)(orow0 + m * 16 + r) * N + (ocol0 + n * 16)] =
              f2bf(__expf(acc[m][n][r] * scale));
  } else {
    float* O = (float*)C;
    #pragma unroll
    for (int m = 0; m < FM; ++m)
      #pragma unroll
      for (int n = 0; n < FN; ++n)
        #pragma unroll
        for (int r = 0; r < 4; ++r)
          O[(size_t)(orow0 + m * 16 + r) * N + (ocol0 + n * 16)] =
              acc[m][n][r];
  }
}

extern "C" void kernel_launch(void* const* d_in, const int* in_sizes, int n_in,
                              void* d_out, int out_size, void* d_ws,
                              size_t ws_size, hipStream_t stream) {
  const float* Q = (const float*)d_in[0];
  const float* K = (const float*)d_in[1];
  const float* V = (const float*)d_in[2];
  float* out = (float*)d_out;

  char* ws = (char*)d_ws;
  unsigned short* Qb = (unsigned short*)(ws);                        // 8 MB
  unsigned short* Kb = (unsigned short*)(ws + ((size_t)8 << 20));    // 8 MB
  unsigned short* E  = (unsigned short*)(ws + ((size_t)16 << 20));   // 32 MB
  unsigned short* Vt = (unsigned short*)(ws + ((size_t)48 << 20));   // 8 MB
  float*          l  = (float*)(ws + ((size_t)56 << 20));            // 16 KB

  hipMemsetAsync(l, 0, SK_ * sizeof(float), stream);

  conv_kernel<<<(SQ_ * D_ / 4 + 255) / 256, 256, 0, stream>>>(Q, Qb, SQ_ * D_ / 4);
  conv_kernel<<<(SK_ * D_ / 4 + 255) / 256, 256, 0, stream>>>(K, Kb, SK_ * D_ / 4);

  // E = exp(Q K^T / SK), bf16
  gemm_bt_kernel<4, 4, true><<<dim3(SK_ / 128, SQ_ / 128), 256, 0, stream>>>(
      Qb, Kb, (void*)E, SK_, D_, 1.0f / (float)SK_);

  // l_j = sum_i E[i][j]
  colsum_kernel<<<dim3(SK_ / 256, SQ_ / 256), 256, 0, stream>>>(E, l);

  // Vt[d][j] = V[j][d] / l[j], bf16
  transv_kernel<<<dim3(SK_ / 64, DV_ / 64), 256, 0, stream>>>(V, l, Vt);

  // O = E @ V'  (A=E [SQ][SK], B=Vt [DV][SK] -> NT-gemm), fp32 out
  gemm_bt_kernel<2, 4, false><<<dim3(DV_ / 128, SQ_ / 64), 256, 0, stream>>>(
      E, Vt, (void*)d_out, DV_, SK_, 1.0f);

  (void)in_sizes; (void)n_in; (void)out_size; (void)ws_size; (void)out;
}

// Round 2
// 112.807 us; speedup vs baseline: 1.1815x; 1.1815x over previous
//
#include <hip/hip_runtime.h>
#include <hip/hip_bf16.h>
#include <stdint.h>

#define SQ_  4096
#define SK_  4096
#define D_   1024
#define DV_  1024

typedef __attribute__((ext_vector_type(8))) __bf16 bf16x8;
typedef __attribute__((ext_vector_type(4))) float  f32x4;
typedef __attribute__((ext_vector_type(4))) int    i32x4;
typedef __attribute__((ext_vector_type(8))) int    i32x8;

__device__ __forceinline__ unsigned short f2bf(float f) {
  union { float f; unsigned u; } a; a.f = f;
  unsigned u = a.u;
  return (unsigned short)((u + 0x7FFFu + ((u >> 16) & 1u)) >> 16);  // RNE
}
__device__ __forceinline__ float bf2f(unsigned short h) {
  union { unsigned u; float f; } a; a.u = ((unsigned)h) << 16;
  return a.f;
}

__device__ __forceinline__ void gload_lds16(const void* gp, void* lp) {
  auto g1 = reinterpret_cast<__attribute__((address_space(1))) uint32_t*>(
      reinterpret_cast<uintptr_t>(gp));
  auto l3 = reinterpret_cast<__attribute__((address_space(3))) uint32_t*>(
      reinterpret_cast<uintptr_t>(lp));
  __builtin_amdgcn_global_load_lds(g1, l3, 16, 0, 0);
}

// ---------------- fp32 -> fp8 e4m3 (OCP) conversion, 8/thread ---------------
__global__ void conv8_kernel(const float* __restrict__ in,
                             unsigned int* __restrict__ out, int n8) {
  int i = blockIdx.x * blockDim.x + threadIdx.x;
  if (i >= n8) return;
  const float4* p = reinterpret_cast<const float4*>(in) + (size_t)i * 2;
  float4 v0 = p[0], v1 = p[1];
  int d0 = __builtin_amdgcn_cvt_pk_fp8_f32(v0.x, v0.y, 0, false);
  d0     = __builtin_amdgcn_cvt_pk_fp8_f32(v0.z, v0.w, d0, true);
  int d1 = __builtin_amdgcn_cvt_pk_fp8_f32(v1.x, v1.y, 0, false);
  d1     = __builtin_amdgcn_cvt_pk_fp8_f32(v1.z, v1.w, d1, true);
  uint2 o; o.x = (unsigned)d0; o.y = (unsigned)d1;
  reinterpret_cast<uint2*>(out)[i] = o;
}

// -------- column partial sums of E (deterministic, no atomics) --------------
// grid (SK_/512, SQ_/128): block sums 128 rows x 512 cols (2 cols/thread).
__global__ void colsum_part_kernel(const unsigned short* __restrict__ E,
                                   float* __restrict__ lpart) {
  int j0 = (blockIdx.x * 256 + threadIdx.x) * 2;
  int i0 = blockIdx.y * 128;
  const unsigned short* p = E + (size_t)i0 * SK_ + j0;
  float s0 = 0.f, s1 = 0.f;
  #pragma unroll 8
  for (int i = 0; i < 128; ++i) {
    ushort2 v = *reinterpret_cast<const ushort2*>(p);
    s0 += bf2f(v.x); s1 += bf2f(v.y);
    p += SK_;
  }
  float2 o; o.x = s0; o.y = s1;
  reinterpret_cast<float2*>(lpart + (size_t)blockIdx.y * SK_ + j0)[0] = o;
}

__global__ void colsum_fin_kernel(const float* __restrict__ lpart,
                                  float* __restrict__ l) {
  int j = blockIdx.x * 256 + threadIdx.x;
  float s = 0.f;
  #pragma unroll
  for (int y = 0; y < 32; ++y) s += lpart[(size_t)y * SK_ + j];
  l[j] = s;
}

// ------------- V' = V / l, transposed to [DV][SK] bf16 -----------------------
__global__ void transv_kernel(const float* __restrict__ V,
                              const float* __restrict__ l,
                              unsigned short* __restrict__ Vt) {
  __shared__ float tile[64][65];
  int j0 = blockIdx.x * 64;           // SK dim
  int d0 = blockIdx.y * 64;           // DV dim
  int t  = threadIdx.x;
  int tr = t >> 6;                    // 0..3
  int tc = t & 63;                    // 0..63
  #pragma unroll
  for (int rr = 0; rr < 16; ++rr) {
    int j = rr * 4 + tr;
    tile[j][tc] = V[(size_t)(j0 + j) * DV_ + d0 + tc];
  }
  __syncthreads();
  float inv = 1.0f / l[j0 + tc];      // divisor indexed by j = tc
  #pragma unroll
  for (int rr = 0; rr < 16; ++rr) {
    int d = rr * 4 + tr;
    Vt[(size_t)(d0 + d) * SK_ + j0 + tc] = f2bf(tile[tc][d] * inv);
  }
}

// ============ GEMM1: E = exp(A*B^T*scale), fp8 MX (scale=1.0) ================
// A [M][K] bytes, B [N][K] bytes, K contiguous. BM=BN=BK=128.
// LDS rows are 128B = 8 x 16B slots, XOR-swizzled exactly like the bf16 path:
// physical slot p_phys = p_log ^ (row&7); staging pre-swizzles the GLOBAL src.
__global__ __launch_bounds__(256, 2)
void gemm8_exp_kernel(const unsigned char* __restrict__ A,
                      const unsigned char* __restrict__ B,
                      unsigned short* __restrict__ E,
                      int N, int K, float scale) {
  __shared__ __align__(16) unsigned char As[128 * 128];
  __shared__ __align__(16) unsigned char Bs[128 * 128];

  const int t    = threadIdx.x;
  const int lane = t & 63;
  const int wave = t >> 6;
  const int wr   = wave >> 1, wc = wave & 1;
  const int lr   = lane & 15;         // row(A frag) / col(B frag) / D col
  const int lk   = lane >> 4;         // k-block 0..3 (32 bytes each)

  const int m0 = blockIdx.y * 128;
  const int n0 = blockIdx.x * 128;

  f32x4 acc[4][4] = {};

  for (int k0 = 0; k0 < K; k0 += 128) {
    #pragma unroll
    for (int it = 0; it < 4; ++it) {
      int s = it * 256 + t;
      int row = s >> 3, p = s & 7;
      int k16 = p ^ (row & 7);
      gload_lds16(A + (size_t)(m0 + row) * K + k0 + k16 * 16, As + s * 16);
    }
    #pragma unroll
    for (int it = 0; it < 4; ++it) {
      int s = it * 256 + t;
      int row = s >> 3, p = s & 7;
      int k16 = p ^ (row & 7);
      gload_lds16(B + (size_t)(n0 + row) * K + k0 + k16 * 16, Bs + s * 16);
    }
    __syncthreads();

    i32x8 af[4], bfr[4];
    #pragma unroll
    for (int m = 0; m < 4; ++m) {
      int r = wr * 64 + m * 16 + lr;
      int s0 = (2 * lk) ^ (r & 7), s1 = (2 * lk + 1) ^ (r & 7);
      i32x4 lo = *reinterpret_cast<const i32x4*>(As + r * 128 + s0 * 16);
      i32x4 hi = *reinterpret_cast<const i32x4*>(As + r * 128 + s1 * 16);
      af[m][0] = lo[0]; af[m][1] = lo[1]; af[m][2] = lo[2]; af[m][3] = lo[3];
      af[m][4] = hi[0]; af[m][5] = hi[1]; af[m][6] = hi[2]; af[m][7] = hi[3];
    }
    #pragma unroll
    for (int n = 0; n < 4; ++n) {
      int r = wc * 64 + n * 16 + lr;
      int s0 = (2 * lk) ^ (r & 7), s1 = (2 * lk + 1) ^ (r & 7);
      i32x4 lo = *reinterpret_cast<const i32x4*>(Bs + r * 128 + s0 * 16);
      i32x4 hi = *reinterpret_cast<const i32x4*>(Bs + r * 128 + s1 * 16);
      bfr[n][0] = lo[0]; bfr[n][1] = lo[1]; bfr[n][2] = lo[2]; bfr[n][3] = lo[3];
      bfr[n][4] = hi[0]; bfr[n][5] = hi[1]; bfr[n][6] = hi[2]; bfr[n][7] = hi[3];
    }
    #pragma unroll
    for (int m = 0; m < 4; ++m)
      #pragma unroll
      for (int n = 0; n < 4; ++n)
        acc[m][n] = __builtin_amdgcn_mfma_scale_f32_16x16x128_f8f6f4(
            af[m], bfr[n], acc[m][n], 0, 0, 0, 127, 0, 127);
    __syncthreads();
  }

  const int orow0 = m0 + wr * 64 + lk * 4;
  const int ocol0 = n0 + wc * 64 + lr;
  #pragma unroll
  for (int m = 0; m < 4; ++m)
    #pragma unroll
    for (int n = 0; n < 4; ++n)
      #pragma unroll
      for (int r = 0; r < 4; ++r)
        E[(size_t)(orow0 + m * 16 + r) * N + (ocol0 + n * 16)] =
            f2bf(__expf(acc[m][n][r] * scale));
}

// ---------------- bf16 GEMM: C[M][N] = A[M][K] * B[N][K]^T (GEMM2) -----------
template <int FM, int FN>
__global__ __launch_bounds__(256, 2)
void gemm_bt_kernel(const unsigned short* __restrict__ A,
                    const unsigned short* __restrict__ B,
                    float* __restrict__ C,
                    int N, int K) {
  constexpr int BM = FM * 32;
  constexpr int BN = FN * 32;
  constexpr int BK = 64;
  __shared__ __align__(16) unsigned short As[BM * BK];
  __shared__ __align__(16) unsigned short Bs[BN * BK];

  const int t    = threadIdx.x;
  const int lane = t & 63;
  const int wave = t >> 6;
  const int wr   = wave >> 1, wc = wave & 1;
  const int lr   = lane & 15;
  const int lk   = lane >> 4;

  const int m0 = blockIdx.y * BM;
  const int n0 = blockIdx.x * BN;

  f32x4 acc[FM][FN] = {};

  for (int k0 = 0; k0 < K; k0 += BK) {
    #pragma unroll
    for (int it = 0; it < BM / 32; ++it) {
      int s = it * 256 + t;
      int row = s >> 3, p = s & 7;
      int k16 = p ^ (row & 7);
      gload_lds16(A + (size_t)(m0 + row) * K + k0 + k16 * 8, As + s * 8);
    }
    #pragma unroll
    for (int it = 0; it < BN / 32; ++it) {
      int s = it * 256 + t;
      int row = s >> 3, p = s & 7;
      int k16 = p ^ (row & 7);
      gload_lds16(B + (size_t)(n0 + row) * K + k0 + k16 * 8, Bs + s * 8);
    }
    __syncthreads();

    #pragma unroll
    for (int kk = 0; kk < 2; ++kk) {
      bf16x8 af[FM], bfr[FN];
      #pragma unroll
      for (int m = 0; m < FM; ++m) {
        int r = wr * (FM * 16) + m * 16 + lr;
        int k16 = kk * 4 + lk;
        af[m] = *reinterpret_cast<const bf16x8*>(
            As + r * BK + ((k16 ^ (r & 7)) * 8));
      }
      #pragma unroll
      for (int n = 0; n < FN; ++n) {
        int r = wc * (FN * 16) + n * 16 + lr;
        int k16 = kk * 4 + lk;
        bfr[n] = *reinterpret_cast<const bf16x8*>(
            Bs + r * BK + ((k16 ^ (r & 7)) * 8));
      }
      #pragma unroll
      for (int m = 0; m < FM; ++m)
        #pragma unroll
        for (int n = 0; n < FN; ++n)
          acc[m][n] = __builtin_amdgcn_mfma_f32_16x16x32_bf16(
              af[m], bfr[n], acc[m][n], 0, 0, 0);
    }
    __syncthreads();
  }

  const int orow0 = m0 + wr * FM * 16 + lk * 4;
  const int ocol0 = n0 + wc * FN * 16 + lr;
  #pragma unroll
  for (int m = 0; m < FM; ++m)
    #pragma unroll
    for (int n = 0; n < FN; ++n)
      #pragma unroll
      for (int r = 0; r < 4; ++r)
        C[(size_t)(orow0 + m * 16 + r) * N + (ocol0 + n * 16)] =
            acc[m][n][r];
}

extern "C" void kernel_launch(void* const* d_in, const int* in_sizes, int n_in,
                              void* d_out, int out_size, void* d_ws,
                              size_t ws_size, hipStream_t stream) {
  const float* Q = (const float*)d_in[0];
  const float* K = (const float*)d_in[1];
  const float* V = (const float*)d_in[2];

  char* ws = (char*)d_ws;
  unsigned char*  Q8 = (unsigned char*)(ws);                          // 4 MB
  unsigned char*  K8 = (unsigned char*)(ws + ((size_t)4 << 20));      // 4 MB
  unsigned short* E  = (unsigned short*)(ws + ((size_t)16 << 20));    // 32 MB
  unsigned short* Vt = (unsigned short*)(ws + ((size_t)48 << 20));    // 8 MB
  float*          l  = (float*)(ws + ((size_t)56 << 20));             // 16 KB
  float*       lpart = (float*)(ws + ((size_t)56 << 20) + (64 << 10)); // 512 KB

  conv8_kernel<<<SQ_ * D_ / 8 / 256, 256, 0, stream>>>(Q, (unsigned*)Q8,
                                                       SQ_ * D_ / 8);
  conv8_kernel<<<SK_ * D_ / 8 / 256, 256, 0, stream>>>(K, (unsigned*)K8,
                                                       SK_ * D_ / 8);

  // E = exp(Q K^T / SK), bf16  (fp8 MX inputs, unit block scales)
  gemm8_exp_kernel<<<dim3(SK_ / 128, SQ_ / 128), 256, 0, stream>>>(
      Q8, K8, E, SK_, D_, 1.0f / (float)SK_);

  // l_j = sum_i E[i][j]  (deterministic two-stage)
  colsum_part_kernel<<<dim3(SK_ / 512, SQ_ / 128), 256, 0, stream>>>(E, lpart);
  colsum_fin_kernel<<<SK_ / 256, 256, 0, stream>>>(lpart, l);

  // Vt[d][j] = V[j][d] / l[j], bf16
  transv_kernel<<<dim3(SK_ / 64, DV_ / 64), 256, 0, stream>>>(V, l, Vt);

  // O = E @ V'  (A=E [SQ][SK], B=Vt [DV][SK] -> NT-gemm), fp32 out
  gemm_bt_kernel<2, 4><<<dim3(DV_ / 128, SQ_ / 64), 256, 0, stream>>>(
      E, Vt, (float*)d_out, DV_, SK_);

  (void)in_sizes; (void)n_in; (void)out_size; (void)ws_size;
}